// Round 5
// baseline (586.840 us; speedup 1.0000x reference)
//
#include <hip/hip_runtime.h>
#include <hip/hip_fp16.h>

// Problem constants
#define ROWS_TOTAL 131072          // SENSORS * TSTEPS (2^17)
#define NNZ        30000000
#define NGROUPS    (NNZ / 4)       // 7,500,000 vec4 groups

// Range / accumulation structure
#define NRANGES  8
#define BINS     (ROWS_TOTAL / NRANGES)   // 16384 bins = 64 KB LDS
#define NSLICES  64                       // accum grid = NSLICES x 8 = 512 blocks
#define ATHREADS 1024
#define MAXNB2   64

// Binned-pair regions: mean/range = 3.75M, binomial sigma ~1.8K.
// Slack 65536 covers stat spread + sentinel/alignment padding.
#define RCAP        3815536               // multiple of 4
#define GCNT_STRIDE 16                    // one counter per 64B line

// pack_bin geometry: 8 waves/block, wave w owns range w.
#define PB_THREADS   512
#define PB_BLOCKS    1024                 // 4 blocks/CU x 256 CUs (wave-capped)
#define CHUNK_GROUPS 1024
#define CHUNK_WORDS  (CHUNK_GROUPS * 4)   // 4096 words = 16 KB
#define NCHUNKS      ((NGROUPS + CHUNK_GROUPS - 1) / CHUNK_GROUPS)   // 7325
#define FCAP         768                  // per-wave FIFO words; mean 512, +12 sigma

// flat_field[c] = field_map.T.flat[c] = field[(c & 255) * 256 + (c >> 8)]
__device__ __forceinline__ int colmap(int c) {
    return ((c & 255) << 8) | (c >> 8);
}

// Pack (row:17 bits) << 15 | f15(contrib). f15 = s1e5m9, rel err <= 2^-10.
// (row, +0.0) packs to (row<<15): adds 0.0 into a bin -> harmless sentinel.
__device__ __forceinline__ unsigned pack_pair(int row, float val) {
    unsigned hb = __half_as_ushort(__float2half(val));   // round-nearest fp16
    unsigned f15 = (hb + 1u) >> 1;                       // round LSB away
    return ((unsigned)row << 15) | f15;
}

__device__ __forceinline__ float unpack_val(unsigned w) {
    return __half2float(__ushort_as_half((unsigned short)((w & 0x7FFFu) << 1)));
}

// ---------------- Phase 0: zero gcnt + out in ONE dispatch -------------------
// Makes the graph replay-safe (no reliance on harness memsets).
__global__ __launch_bounds__(256) void zero_init(
    unsigned* __restrict__ gcnt,        // 256 words (incl. padding lines)
    float*    __restrict__ out)         // ROWS_TOTAL floats
{
    const int i = blockIdx.x * 256 + threadIdx.x;       // grid 128 x 256
    ((float4*)out)[i] = make_float4(0.f, 0.f, 0.f, 0.f); // 32768 float4 = 2^17
    if (blockIdx.x == 0 && threadIdx.x < NRANGES * GCNT_STRIDE)
        gcnt[threadIdx.x] = 0u;
}

// ---------------- Phase 1: software-pipelined gather-pack-BIN ----------------
// (byte-identical logic to the r3 version that passed at 228 us)
__global__ __launch_bounds__(PB_THREADS) void pack_bin(
    const float* __restrict__ field,
    const int*   __restrict__ idx_row,
    const int*   __restrict__ idx_col,
    const float* __restrict__ vals,
    unsigned*    __restrict__ binned,   // [NRANGES][RCAP]
    unsigned*    __restrict__ gcnt)     // [NRANGES] strided by GCNT_STRIDE
{
    __shared__ __align__(16) unsigned chunk[CHUNK_WORDS];          // 16 KB
    __shared__ __align__(16) unsigned fifo[NRANGES][FCAP];         // 24 KB

    const int tid  = threadIdx.x;
    const int lane = tid & 63;
    const unsigned wid = (unsigned)(tid >> 6);          // this wave's range
    unsigned* const dst = binned + (size_t)wid * RCAP;
    const unsigned long long below = (1ull << lane) - 1ull;

    const int c0 = (int)(((long long)blockIdx.x       * NCHUNKS) / gridDim.x);
    const int c1 = (int)(((long long)(blockIdx.x + 1) * NCHUNKS) / gridDim.x);

    #define LDGRP(G, R, C, V) {                                              \
        if ((G) < NGROUPS) {                                                 \
            R = ((const int4*)idx_row)[(G)];                                 \
            C = ((const int4*)idx_col)[(G)];                                 \
            V = ((const float4*)vals)[(G)];                                  \
        } else {                                                             \
            const int b_ = (G) << 2;                                         \
            R.x = ( b_      << 5) & 131071; R.y = ((b_ + 1) << 5) & 131071;  \
            R.z = ((b_ + 2) << 5) & 131071; R.w = ((b_ + 3) << 5) & 131071;  \
            C = make_int4(0, 0, 0, 0);                                       \
            V = make_float4(0.f, 0.f, 0.f, 0.f);                             \
        } }

    #define LOADREG(CK) {                                                    \
        const int gA_ = (CK) * CHUNK_GROUPS + tid;                           \
        const int gB_ = gA_ + PB_THREADS;                                    \
        LDGRP(gA_, ra, ca, va);                                              \
        LDGRP(gB_, rb, cb, vb); }

    #define GATHERS() {                                                      \
        fa0 = va.x * field[colmap(ca.x)]; fa1 = va.y * field[colmap(ca.y)];  \
        fa2 = va.z * field[colmap(ca.z)]; fa3 = va.w * field[colmap(ca.w)];  \
        fb0 = vb.x * field[colmap(cb.x)]; fb1 = vb.y * field[colmap(cb.y)];  \
        fb2 = vb.z * field[colmap(cb.z)]; fb3 = vb.w * field[colmap(cb.w)]; }

    int4 ra, ca, rb, cb;
    float4 va, vb;
    float fa0, fa1, fa2, fa3, fb0, fb1, fb2, fb3;

    LOADREG(c0);
    GATHERS();

    for (int ck = c0; ck < c1; ++ck) {
        // ---- pack current chunk (pure VALU + 2 ds_write_b128) ----
        uint4 oA, oB;
        oA.x = pack_pair(ra.x, fa0); oA.y = pack_pair(ra.y, fa1);
        oA.z = pack_pair(ra.z, fa2); oA.w = pack_pair(ra.w, fa3);
        oB.x = pack_pair(rb.x, fb0); oB.y = pack_pair(rb.y, fb1);
        oB.z = pack_pair(rb.z, fb2); oB.w = pack_pair(rb.w, fb3);
        *(uint4*)&chunk[(unsigned)tid << 2]                  = oA;
        *(uint4*)&chunk[(unsigned)(PB_THREADS + tid) << 2]   = oB;
        __syncthreads();

        const bool more = (ck + 1 < c1);
        if (more) LOADREG(ck + 1);          // streams fly during scan

        // ---- scan: extract words with (word >> 29) == wid ----
        unsigned cnt = 0;
        const uint4* chunk4 = (const uint4*)chunk;
        #pragma unroll 4
        for (int s = 0; s < CHUNK_WORDS / 256; ++s) {   // 16 b128 steps
            const uint4 q = chunk4[(s << 6) + lane];
            #define SCAN1(W) {                                                  \
                const unsigned w_ = (W);                                        \
                const bool hit_ = ((w_ >> 29) == wid);                          \
                const unsigned long long m_ = __ballot(hit_);                   \
                if (hit_) {                                                     \
                    const unsigned off_ = cnt + (unsigned)__popcll(m_ & below); \
                    if (off_ < (unsigned)FCAP) fifo[wid][off_] = w_;            \
                    else {  /* overflow spill: 4-slot resv keeps alignment */   \
                        unsigned gs_ = atomicAdd(&gcnt[wid * GCNT_STRIDE], 4u); \
                        if (gs_ + 4u <= (unsigned)RCAP) {                       \
                            uint4 sp_ = make_uint4(w_, 0u, 0u, 0u);             \
                            *(uint4*)(dst + gs_) = sp_;                         \
                        }                                                       \
                    }                                                           \
                }                                                               \
                cnt += (unsigned)__popcll(m_);                                  \
            }
            SCAN1(q.x); SCAN1(q.y); SCAN1(q.z); SCAN1(q.w);
            #undef SCAN1
        }
        if (cnt > (unsigned)FCAP) cnt = (unsigned)FCAP;
        const unsigned cntR = (cnt + 3u) & ~3u;         // pad to x4 with zeros
        if (lane < (int)(cntR - cnt)) fifo[wid][cnt + (unsigned)lane] = 0u;

        if (more) GATHERS();                // gathers fly during flush+barrier

        // same-wave ds ordering guard before flush reads of fifo
        asm volatile("s_waitcnt lgkmcnt(0)" ::: "memory");

        // ---- bulk-reserve + coalesced uint4 flush ----
        unsigned gs0 = 0;
        if (lane == 0) gs0 = atomicAdd(&gcnt[wid * GCNT_STRIDE], cntR);
        gs0 = __shfl(gs0, 0);

        const unsigned n4 = cntR >> 2;                  // <= 192
        const uint4* f4 = (const uint4*)fifo[wid];
        for (unsigned t = (unsigned)lane; t < n4; t += 64u) {
            const unsigned o4 = gs0 + (t << 2);
            if (o4 + 4u <= (unsigned)RCAP)
                *(uint4*)(dst + o4) = f4[t];
        }
        __syncthreads();    // chunk + fifo reuse next iteration
    }
    #undef LOADREG
    #undef LDGRP
    #undef GATHERS
}

// ---------------- Phase 2: single-read accumulation, atomic out --------------
// Grid = NSLICES x 8. Block (j,p) accumulates slice j of range p in LDS, then
// adds its partial bins straight into out[] with fp32 global atomics:
// no copies buffer, no reduce dispatch. 512 blocks x 16384 adds = 8.4M
// wave-coalesced atomics to distinct addresses (~5-10 us).
__global__ __launch_bounds__(ATHREADS) void bin_accum_atomic(
    const unsigned* __restrict__ binned,
    const unsigned* __restrict__ gcnt,
    float*          __restrict__ out)
{
    __shared__ float bins[BINS];
    const int j = blockIdx.x >> 3;
    const int p = blockIdx.x & 7;

    for (int t = threadIdx.x; t < BINS; t += ATHREADS) bins[t] = 0.0f;
    __syncthreads();

    unsigned n = gcnt[p * GCNT_STRIDE];
    if (n > (unsigned)RCAP) n = (unsigned)RCAP;
    const unsigned n4 = n >> 2;
    const uint4* src = (const uint4*)(binned + (size_t)p * RCAP);
    const int start = (int)(((long long)j       * (long long)n4) / NSLICES);
    const int end   = (int)(((long long)(j + 1) * (long long)n4) / NSLICES);
    const unsigned lo = (unsigned)p << 14;

    #pragma unroll 4
    for (int g = start + threadIdx.x; g < end; g += ATHREADS) {
        const uint4 w = src[g];
        unsigned l0 = (w.x >> 15) - lo;
        if (l0 < (unsigned)BINS) atomicAdd(&bins[l0], unpack_val(w.x));
        unsigned l1 = (w.y >> 15) - lo;
        if (l1 < (unsigned)BINS) atomicAdd(&bins[l1], unpack_val(w.y));
        unsigned l2 = (w.z >> 15) - lo;
        if (l2 < (unsigned)BINS) atomicAdd(&bins[l2], unpack_val(w.z));
        unsigned l3 = (w.w >> 15) - lo;
        if (l3 < (unsigned)BINS) atomicAdd(&bins[l3], unpack_val(w.w));
    }
    __syncthreads();

    float* const obase = out + lo;
    for (int t = threadIdx.x; t < BINS; t += ATHREADS)
        atomicAdd(&obase[t], bins[t]);
}

// ---------------- Legacy path (fallback): pack + skip-scan -------------------
__global__ __launch_bounds__(1024) void pack_pairs(
    const float* __restrict__ field,
    const int*   __restrict__ idx_row,
    const int*   __restrict__ idx_col,
    const float* __restrict__ vals,
    unsigned*    __restrict__ pairs)     // [NNZ]
{
    const int stride = gridDim.x * blockDim.x;
    #pragma unroll 2
    for (int i = blockIdx.x * 1024 + threadIdx.x; i < NGROUPS; i += stride) {
        const int4   r = ((const int4*)idx_row)[i];
        const int4   c = ((const int4*)idx_col)[i];
        const float4 v = ((const float4*)vals)[i];
        uint4 o;
        o.x = pack_pair(r.x, v.x * field[colmap(c.x)]);
        o.y = pack_pair(r.y, v.y * field[colmap(c.y)]);
        o.z = pack_pair(r.z, v.z * field[colmap(c.z)]);
        o.w = pack_pair(r.w, v.w * field[colmap(c.w)]);
        ((uint4*)pairs)[i] = o;
    }
}

__global__ __launch_bounds__(ATHREADS) void range_accum(
    const unsigned* __restrict__ pairs,
    float*          __restrict__ copies,
    int nb2)
{
    __shared__ float bins[BINS];
    const int j  = blockIdx.x >> 3;
    const int p  = blockIdx.x & 7;
    const unsigned lo = (unsigned)p << 14;

    for (int t = threadIdx.x; t < BINS; t += ATHREADS) bins[t] = 0.0f;
    __syncthreads();

    const int start = (int)(((long long)j       * NGROUPS) / nb2);
    const int end   = (int)(((long long)(j + 1) * NGROUPS) / nb2);

    #pragma unroll 2
    for (int g = start + threadIdx.x; g < end; g += ATHREADS) {
        const uint4 w = ((const uint4*)pairs)[g];
        unsigned l0 = (w.x >> 15) - lo;
        if (l0 < (unsigned)BINS) atomicAdd(&bins[l0], unpack_val(w.x));
        unsigned l1 = (w.y >> 15) - lo;
        if (l1 < (unsigned)BINS) atomicAdd(&bins[l1], unpack_val(w.y));
        unsigned l2 = (w.z >> 15) - lo;
        if (l2 < (unsigned)BINS) atomicAdd(&bins[l2], unpack_val(w.z));
        unsigned l3 = (w.w >> 15) - lo;
        if (l3 < (unsigned)BINS) atomicAdd(&bins[l3], unpack_val(w.w));
    }
    __syncthreads();

    float* dst = copies + ((size_t)p * nb2 + j) * BINS;
    for (int t = threadIdx.x; t < BINS; t += ATHREADS) dst[t] = bins[t];
}

__global__ __launch_bounds__(256) void reduce_copies(
    const float* __restrict__ copies,
    float*       __restrict__ out,
    int nb2)
{
    const int r   = blockIdx.x * 256 + threadIdx.x;     // 0..ROWS_TOTAL-1
    const int p   = r >> 14;
    const int bin = r & (BINS - 1);
    const float* base = copies + ((size_t)p * nb2) * BINS + bin;
    float s = 0.0f;
    #pragma unroll 16
    for (int j = 0; j < nb2; ++j)
        s += base[(size_t)j * BINS];
    out[r] = s;
}

// ---------------- Fallback: global-atomic kernel -----------------------------
__global__ __launch_bounds__(256) void coo_scatter_kernel(
    const float* __restrict__ field,
    const int*   __restrict__ idx_row,
    const int*   __restrict__ idx_col,
    const float* __restrict__ vals,
    float*       __restrict__ out)
{
    const int i = blockIdx.x * 256 + threadIdx.x;
    if (i >= NGROUPS) return;
    const int4   r = ((const int4*)idx_row)[i];
    const int4   c = ((const int4*)idx_col)[i];
    const float4 v = ((const float4*)vals)[i];
    atomicAdd(&out[r.x], v.x * field[colmap(c.x)]);
    atomicAdd(&out[r.y], v.y * field[colmap(c.y)]);
    atomicAdd(&out[r.z], v.z * field[colmap(c.z)]);
    atomicAdd(&out[r.w], v.w * field[colmap(c.w)]);
}

extern "C" void kernel_launch(void* const* d_in, const int* in_sizes, int n_in,
                              void* d_out, int out_size, void* d_ws, size_t ws_size,
                              hipStream_t stream) {
    const float* field   = (const float*)d_in[0];
    const int*   idx_row = (const int*)d_in[1];
    const int*   idx_col = (const int*)d_in[2];
    const float* vals    = (const float*)d_in[3];
    float*       out     = (float*)d_out;

    const size_t binned_bytes = (size_t)NRANGES * RCAP * sizeof(unsigned);   // ~122.1 MB
    const size_t cnt_bytes    = 1024;
    const size_t pair_bytes   = (size_t)NNZ * sizeof(unsigned);              // 120 MB
    const size_t copy_slice   = (size_t)NRANGES * BINS * sizeof(float);      // 512 KB

    if (ws_size >= binned_bytes + cnt_bytes) {
        // ---- binned path, 3 dispatches: zero | pack | accum+atomic-out ----
        unsigned* binned = (unsigned*)d_ws;
        unsigned* gcnt   = (unsigned*)((char*)d_ws + binned_bytes);

        zero_init<<<ROWS_TOTAL / (256 * 4), 256, 0, stream>>>(gcnt, out);
        pack_bin<<<PB_BLOCKS, PB_THREADS, 0, stream>>>(field, idx_row, idx_col,
                                                       vals, binned, gcnt);
        bin_accum_atomic<<<NSLICES * NRANGES, ATHREADS, 0, stream>>>(
            binned, gcnt, out);
    } else if (ws_size >= pair_bytes + 2 * copy_slice) {
        // ---- legacy skip-scan path ----
        unsigned* pairs  = (unsigned*)d_ws;
        float*    copies = (float*)((char*)d_ws + pair_bytes);

        int nb2 = (int)((ws_size - pair_bytes) / copy_slice);
        if (nb2 > MAXNB2) nb2 = MAXNB2;

        pack_pairs<<<512, 1024, 0, stream>>>(field, idx_row, idx_col, vals, pairs);
        range_accum<<<nb2 * NRANGES, ATHREADS, 0, stream>>>(pairs, copies, nb2);
        reduce_copies<<<ROWS_TOTAL / 256, 256, 0, stream>>>(copies, out, nb2);
    } else {
        hipMemsetAsync(out, 0, (size_t)out_size * sizeof(float), stream);
        coo_scatter_kernel<<<(NGROUPS + 255) / 256, 256, 0, stream>>>(
            field, idx_row, idx_col, vals, out);
    }
}

// Round 6
// 581.505 us; speedup vs baseline: 1.0092x; 1.0092x over previous
//
#include <hip/hip_runtime.h>
#include <hip/hip_fp16.h>

// Problem constants
#define ROWS_TOTAL 131072          // SENSORS * TSTEPS (2^17)
#define NNZ        30000000
#define NGROUPS    (NNZ / 4)       // 7,500,000 vec4 groups

// Range / accumulation structure
#define NRANGES  8
#define BINS     (ROWS_TOTAL / NRANGES)   // 16384 bins = 64 KB LDS
#define NSLICES  64                       // accum grid = NSLICES x 8 = 512 blocks
#define ATHREADS 1024
#define MAXNB2   64

// Binned-pair regions: mean/range = 3.75M, binomial sigma ~1.8K.
// Slack 65536 covers stat spread + sentinel/alignment padding.
#define RCAP        3815536               // multiple of 4
#define GCNT_STRIDE 16                    // one counter per 64B line

// pack_bin geometry: 8 waves/block, wave w owns range w.
#define PB_THREADS   512
#define PB_BLOCKS    1024                 // 4 blocks/CU x 256 CUs
#define CHUNK_GROUPS 1024
#define CHUNK_WORDS  (CHUNK_GROUPS * 4)   // 4096 words = 16 KB
#define NCHUNKS      ((NGROUPS + CHUNK_GROUPS - 1) / CHUNK_GROUPS)   // 7325
// FCAP 704 (was 768): LDS = 16KB + 8*704*4 = 38.0 KB -> 4 blocks/CU fit with
// slack (40KB rounded allocation was capping occupancy at 2/CU = 51%).
// Per-chunk per-range count ~ Binom(4096,1/8): mean 512, sigma 21 -> 704 = +9
// sigma; global-spill path covers the ~1e-19 tail anyway.
#define FCAP         704

// flat_field[c] = field_map.T.flat[c] = field[(c & 255) * 256 + (c >> 8)]
__device__ __forceinline__ int colmap(int c) {
    return ((c & 255) << 8) | (c >> 8);
}

// Pack (row:17 bits) << 15 | f15(contrib). f15 = s1e5m9, rel err <= 2^-10.
// (row, +0.0) packs to (row<<15): adds 0.0 into a bin -> harmless sentinel.
__device__ __forceinline__ unsigned pack_pair(int row, float val) {
    unsigned hb = __half_as_ushort(__float2half(val));   // round-nearest fp16
    unsigned f15 = (hb + 1u) >> 1;                       // round LSB away
    return ((unsigned)row << 15) | f15;
}

__device__ __forceinline__ float unpack_val(unsigned w) {
    return __half2float(__ushort_as_half((unsigned short)((w & 0x7FFFu) << 1)));
}

// ---------------- Phase 0: zero gcnt + out in ONE dispatch -------------------
// Makes the graph replay-safe (no reliance on harness memsets).
__global__ __launch_bounds__(256) void zero_init(
    unsigned* __restrict__ gcnt,        // 128 words (incl. padding lines)
    float*    __restrict__ out)         // ROWS_TOTAL floats
{
    const int i = blockIdx.x * 256 + threadIdx.x;       // grid 128 x 256
    ((float4*)out)[i] = make_float4(0.f, 0.f, 0.f, 0.f); // 32768 float4 = 2^17
    if (blockIdx.x == 0 && threadIdx.x < NRANGES * GCNT_STRIDE)
        gcnt[threadIdx.x] = 0u;
}

// ---------------- Phase 1: software-pipelined gather-pack-BIN ----------------
// Per chunk: 512 threads pack 4096 pairs into a 16 KB LDS chunk; each of the
// 8 waves scans the chunk and extracts its own range (rg = word >> 29) into a
// wave-private FIFO via ballot/prefix (no LDS atomics), bulk-reserves global
// slots (1 atomic per wave per chunk), flushes coalesced uint4.
// Pipeline: next chunk's stream loads issue during the scan; next chunk's
// gathers issue during the flush -> pack phase is pure VALU + ds_write.
__global__ __launch_bounds__(PB_THREADS) void pack_bin(
    const float* __restrict__ field,
    const int*   __restrict__ idx_row,
    const int*   __restrict__ idx_col,
    const float* __restrict__ vals,
    unsigned*    __restrict__ binned,   // [NRANGES][RCAP]
    unsigned*    __restrict__ gcnt)     // [NRANGES] strided by GCNT_STRIDE
{
    __shared__ __align__(16) unsigned chunk[CHUNK_WORDS];          // 16 KB
    __shared__ __align__(16) unsigned fifo[NRANGES][FCAP];         // 22 KB

    const int tid  = threadIdx.x;
    const int lane = tid & 63;
    const unsigned wid = (unsigned)(tid >> 6);          // this wave's range
    unsigned* const dst = binned + (size_t)wid * RCAP;
    const unsigned long long below = (1ull << lane) - 1ull;

    const int c0 = (int)(((long long)blockIdx.x       * NCHUNKS) / gridDim.x);
    const int c1 = (int)(((long long)(blockIdx.x + 1) * NCHUNKS) / gridDim.x);

    #define LDGRP(G, R, C, V) {                                              \
        if ((G) < NGROUPS) {                                                 \
            R = ((const int4*)idx_row)[(G)];                                 \
            C = ((const int4*)idx_col)[(G)];                                 \
            V = ((const float4*)vals)[(G)];                                  \
        } else {                                                             \
            const int b_ = (G) << 2;                                         \
            R.x = ( b_      << 5) & 131071; R.y = ((b_ + 1) << 5) & 131071;  \
            R.z = ((b_ + 2) << 5) & 131071; R.w = ((b_ + 3) << 5) & 131071;  \
            C = make_int4(0, 0, 0, 0);                                       \
            V = make_float4(0.f, 0.f, 0.f, 0.f);                             \
        } }

    #define LOADREG(CK) {                                                    \
        const int gA_ = (CK) * CHUNK_GROUPS + tid;                           \
        const int gB_ = gA_ + PB_THREADS;                                    \
        LDGRP(gA_, ra, ca, va);                                              \
        LDGRP(gB_, rb, cb, vb); }

    #define GATHERS() {                                                      \
        fa0 = va.x * field[colmap(ca.x)]; fa1 = va.y * field[colmap(ca.y)];  \
        fa2 = va.z * field[colmap(ca.z)]; fa3 = va.w * field[colmap(ca.w)];  \
        fb0 = vb.x * field[colmap(cb.x)]; fb1 = vb.y * field[colmap(cb.y)];  \
        fb2 = vb.z * field[colmap(cb.z)]; fb3 = vb.w * field[colmap(cb.w)]; }

    int4 ra, ca, rb, cb;
    float4 va, vb;
    float fa0, fa1, fa2, fa3, fb0, fb1, fb2, fb3;

    LOADREG(c0);
    GATHERS();

    for (int ck = c0; ck < c1; ++ck) {
        // ---- pack current chunk (pure VALU + 2 ds_write_b128) ----
        uint4 oA, oB;
        oA.x = pack_pair(ra.x, fa0); oA.y = pack_pair(ra.y, fa1);
        oA.z = pack_pair(ra.z, fa2); oA.w = pack_pair(ra.w, fa3);
        oB.x = pack_pair(rb.x, fb0); oB.y = pack_pair(rb.y, fb1);
        oB.z = pack_pair(rb.z, fb2); oB.w = pack_pair(rb.w, fb3);
        *(uint4*)&chunk[(unsigned)tid << 2]                  = oA;
        *(uint4*)&chunk[(unsigned)(PB_THREADS + tid) << 2]   = oB;
        __syncthreads();

        const bool more = (ck + 1 < c1);
        if (more) LOADREG(ck + 1);          // streams fly during scan

        // ---- scan: extract words with (word >> 29) == wid ----
        unsigned cnt = 0;
        const uint4* chunk4 = (const uint4*)chunk;
        #pragma unroll 4
        for (int s = 0; s < CHUNK_WORDS / 256; ++s) {   // 16 b128 steps
            const uint4 q = chunk4[(s << 6) + lane];
            #define SCAN1(W) {                                                  \
                const unsigned w_ = (W);                                        \
                const bool hit_ = ((w_ >> 29) == wid);                          \
                const unsigned long long m_ = __ballot(hit_);                   \
                if (hit_) {                                                     \
                    const unsigned off_ = cnt + (unsigned)__popcll(m_ & below); \
                    if (off_ < (unsigned)FCAP) fifo[wid][off_] = w_;            \
                    else {  /* overflow spill: 4-slot resv keeps alignment */   \
                        unsigned gs_ = atomicAdd(&gcnt[wid * GCNT_STRIDE], 4u); \
                        if (gs_ + 4u <= (unsigned)RCAP) {                       \
                            uint4 sp_ = make_uint4(w_, 0u, 0u, 0u);             \
                            *(uint4*)(dst + gs_) = sp_;                         \
                        }                                                       \
                    }                                                           \
                }                                                               \
                cnt += (unsigned)__popcll(m_);                                  \
            }
            SCAN1(q.x); SCAN1(q.y); SCAN1(q.z); SCAN1(q.w);
            #undef SCAN1
        }
        if (cnt > (unsigned)FCAP) cnt = (unsigned)FCAP;
        const unsigned cntR = (cnt + 3u) & ~3u;         // pad to x4 with zeros
        if (lane < (int)(cntR - cnt)) fifo[wid][cnt + (unsigned)lane] = 0u;

        if (more) GATHERS();                // gathers fly during flush+barrier

        // same-wave ds ordering guard before flush reads of fifo
        asm volatile("s_waitcnt lgkmcnt(0)" ::: "memory");

        // ---- bulk-reserve + coalesced uint4 flush ----
        unsigned gs0 = 0;
        if (lane == 0) gs0 = atomicAdd(&gcnt[wid * GCNT_STRIDE], cntR);
        gs0 = __shfl(gs0, 0);

        const unsigned n4 = cntR >> 2;                  // <= 176
        const uint4* f4 = (const uint4*)fifo[wid];
        for (unsigned t = (unsigned)lane; t < n4; t += 64u) {
            const unsigned o4 = gs0 + (t << 2);
            if (o4 + 4u <= (unsigned)RCAP)
                *(uint4*)(dst + o4) = f4[t];
        }
        __syncthreads();    // chunk + fifo reuse next iteration
    }
    #undef LOADREG
    #undef LDGRP
    #undef GATHERS
}

// ---------------- Phase 2: single-read accumulation, atomic out --------------
// Grid = NSLICES x 8. Block (j,p) accumulates slice j of range p in LDS, then
// adds its partial bins straight into out[] with fp32 global atomics.
__global__ __launch_bounds__(ATHREADS) void bin_accum_atomic(
    const unsigned* __restrict__ binned,
    const unsigned* __restrict__ gcnt,
    float*          __restrict__ out)
{
    __shared__ float bins[BINS];
    const int j = blockIdx.x >> 3;
    const int p = blockIdx.x & 7;

    for (int t = threadIdx.x; t < BINS; t += ATHREADS) bins[t] = 0.0f;
    __syncthreads();

    unsigned n = gcnt[p * GCNT_STRIDE];
    if (n > (unsigned)RCAP) n = (unsigned)RCAP;
    const unsigned n4 = n >> 2;
    const uint4* src = (const uint4*)(binned + (size_t)p * RCAP);
    const int start = (int)(((long long)j       * (long long)n4) / NSLICES);
    const int end   = (int)(((long long)(j + 1) * (long long)n4) / NSLICES);
    const unsigned lo = (unsigned)p << 14;

    #pragma unroll 4
    for (int g = start + threadIdx.x; g < end; g += ATHREADS) {
        const uint4 w = src[g];
        unsigned l0 = (w.x >> 15) - lo;
        if (l0 < (unsigned)BINS) atomicAdd(&bins[l0], unpack_val(w.x));
        unsigned l1 = (w.y >> 15) - lo;
        if (l1 < (unsigned)BINS) atomicAdd(&bins[l1], unpack_val(w.y));
        unsigned l2 = (w.z >> 15) - lo;
        if (l2 < (unsigned)BINS) atomicAdd(&bins[l2], unpack_val(w.z));
        unsigned l3 = (w.w >> 15) - lo;
        if (l3 < (unsigned)BINS) atomicAdd(&bins[l3], unpack_val(w.w));
    }
    __syncthreads();

    float* const obase = out + lo;
    for (int t = threadIdx.x; t < BINS; t += ATHREADS)
        atomicAdd(&obase[t], bins[t]);
}

// ---------------- Legacy path (fallback): pack + skip-scan -------------------
__global__ __launch_bounds__(1024) void pack_pairs(
    const float* __restrict__ field,
    const int*   __restrict__ idx_row,
    const int*   __restrict__ idx_col,
    const float* __restrict__ vals,
    unsigned*    __restrict__ pairs)     // [NNZ]
{
    const int stride = gridDim.x * blockDim.x;
    #pragma unroll 2
    for (int i = blockIdx.x * 1024 + threadIdx.x; i < NGROUPS; i += stride) {
        const int4   r = ((const int4*)idx_row)[i];
        const int4   c = ((const int4*)idx_col)[i];
        const float4 v = ((const float4*)vals)[i];
        uint4 o;
        o.x = pack_pair(r.x, v.x * field[colmap(c.x)]);
        o.y = pack_pair(r.y, v.y * field[colmap(c.y)]);
        o.z = pack_pair(r.z, v.z * field[colmap(c.z)]);
        o.w = pack_pair(r.w, v.w * field[colmap(c.w)]);
        ((uint4*)pairs)[i] = o;
    }
}

__global__ __launch_bounds__(ATHREADS) void range_accum(
    const unsigned* __restrict__ pairs,
    float*          __restrict__ copies,
    int nb2)
{
    __shared__ float bins[BINS];
    const int j  = blockIdx.x >> 3;
    const int p  = blockIdx.x & 7;
    const unsigned lo = (unsigned)p << 14;

    for (int t = threadIdx.x; t < BINS; t += ATHREADS) bins[t] = 0.0f;
    __syncthreads();

    const int start = (int)(((long long)j       * NGROUPS) / nb2);
    const int end   = (int)(((long long)(j + 1) * NGROUPS) / nb2);

    #pragma unroll 2
    for (int g = start + threadIdx.x; g < end; g += ATHREADS) {
        const uint4 w = ((const uint4*)pairs)[g];
        unsigned l0 = (w.x >> 15) - lo;
        if (l0 < (unsigned)BINS) atomicAdd(&bins[l0], unpack_val(w.x));
        unsigned l1 = (w.y >> 15) - lo;
        if (l1 < (unsigned)BINS) atomicAdd(&bins[l1], unpack_val(w.y));
        unsigned l2 = (w.z >> 15) - lo;
        if (l2 < (unsigned)BINS) atomicAdd(&bins[l2], unpack_val(w.z));
        unsigned l3 = (w.w >> 15) - lo;
        if (l3 < (unsigned)BINS) atomicAdd(&bins[l3], unpack_val(w.w));
    }
    __syncthreads();

    float* dst = copies + ((size_t)p * nb2 + j) * BINS;
    for (int t = threadIdx.x; t < BINS; t += ATHREADS) dst[t] = bins[t];
}

__global__ __launch_bounds__(256) void reduce_copies(
    const float* __restrict__ copies,
    float*       __restrict__ out,
    int nb2)
{
    const int r   = blockIdx.x * 256 + threadIdx.x;     // 0..ROWS_TOTAL-1
    const int p   = r >> 14;
    const int bin = r & (BINS - 1);
    const float* base = copies + ((size_t)p * nb2) * BINS + bin;
    float s = 0.0f;
    #pragma unroll 16
    for (int j = 0; j < nb2; ++j)
        s += base[(size_t)j * BINS];
    out[r] = s;
}

// ---------------- Fallback: global-atomic kernel -----------------------------
__global__ __launch_bounds__(256) void coo_scatter_kernel(
    const float* __restrict__ field,
    const int*   __restrict__ idx_row,
    const int*   __restrict__ idx_col,
    const float* __restrict__ vals,
    float*       __restrict__ out)
{
    const int i = blockIdx.x * 256 + threadIdx.x;
    if (i >= NGROUPS) return;
    const int4   r = ((const int4*)idx_row)[i];
    const int4   c = ((const int4*)idx_col)[i];
    const float4 v = ((const float4*)vals)[i];
    atomicAdd(&out[r.x], v.x * field[colmap(c.x)]);
    atomicAdd(&out[r.y], v.y * field[colmap(c.y)]);
    atomicAdd(&out[r.z], v.z * field[colmap(c.z)]);
    atomicAdd(&out[r.w], v.w * field[colmap(c.w)]);
}

extern "C" void kernel_launch(void* const* d_in, const int* in_sizes, int n_in,
                              void* d_out, int out_size, void* d_ws, size_t ws_size,
                              hipStream_t stream) {
    const float* field   = (const float*)d_in[0];
    const int*   idx_row = (const int*)d_in[1];
    const int*   idx_col = (const int*)d_in[2];
    const float* vals    = (const float*)d_in[3];
    float*       out     = (float*)d_out;

    const size_t binned_bytes = (size_t)NRANGES * RCAP * sizeof(unsigned);   // ~122.1 MB
    const size_t cnt_bytes    = 1024;
    const size_t pair_bytes   = (size_t)NNZ * sizeof(unsigned);              // 120 MB
    const size_t copy_slice   = (size_t)NRANGES * BINS * sizeof(float);      // 512 KB

    if (ws_size >= binned_bytes + cnt_bytes) {
        // ---- binned path, 3 dispatches: zero | pack | accum+atomic-out ----
        unsigned* binned = (unsigned*)d_ws;
        unsigned* gcnt   = (unsigned*)((char*)d_ws + binned_bytes);

        zero_init<<<ROWS_TOTAL / (256 * 4), 256, 0, stream>>>(gcnt, out);
        pack_bin<<<PB_BLOCKS, PB_THREADS, 0, stream>>>(field, idx_row, idx_col,
                                                       vals, binned, gcnt);
        bin_accum_atomic<<<NSLICES * NRANGES, ATHREADS, 0, stream>>>(
            binned, gcnt, out);
    } else if (ws_size >= pair_bytes + 2 * copy_slice) {
        // ---- legacy skip-scan path ----
        unsigned* pairs  = (unsigned*)d_ws;
        float*    copies = (float*)((char*)d_ws + pair_bytes);

        int nb2 = (int)((ws_size - pair_bytes) / copy_slice);
        if (nb2 > MAXNB2) nb2 = MAXNB2;

        pack_pairs<<<512, 1024, 0, stream>>>(field, idx_row, idx_col, vals, pairs);
        range_accum<<<nb2 * NRANGES, ATHREADS, 0, stream>>>(pairs, copies, nb2);
        reduce_copies<<<ROWS_TOTAL / 256, 256, 0, stream>>>(copies, out, nb2);
    } else {
        hipMemsetAsync(out, 0, (size_t)out_size * sizeof(float), stream);
        coo_scatter_kernel<<<(NGROUPS + 255) / 256, 256, 0, stream>>>(
            field, idx_row, idx_col, vals, out);
    }
}